// Round 3
// baseline (1041.868 us; speedup 1.0000x reference)
//
#include <hip/hip_runtime.h>
#include <math.h>

// SimpleAttentionBlock fp32 -> bf16x3 split-GEMM on MFMA (gfx950).
// All GEMMs: A[M,K] (hi/lo bf16) x Bt[N,K] (hi/lo bf16) with fp32 MFMA accum,
// 3 products (hh, hl, lh) ~= fp32 accuracy (~1e-5 rel).

#define D_MODEL 1024
#define DFF_    4096
#define SEQ_    2048
#define NBATCH  4

typedef unsigned short u16;
typedef __attribute__((ext_vector_type(8))) short bf16x8;
typedef __attribute__((ext_vector_type(4))) float f32x4;

__device__ __forceinline__ u16 f2bf(float f) {
    unsigned u = __float_as_uint(f);
    unsigned r = (u + 0x7fffu + ((u >> 16) & 1u)) >> 16;
    return (u16)r;
}
__device__ __forceinline__ float bf2f(u16 h) {
    return __uint_as_float(((unsigned)h) << 16);
}

// ---- async 16B global->LDS. LDS dest must be wave-uniform base + lane*16
// (our staging layout satisfies this: lds offset = (s*256+tid)*16).
__device__ __forceinline__ void gld_lds16(const void* g, void* l) {
#if __has_builtin(__builtin_amdgcn_global_load_lds)
    typedef __attribute__((address_space(1))) const unsigned int as1_u32;
    typedef __attribute__((address_space(3))) unsigned int as3_u32;
    __builtin_amdgcn_global_load_lds((as1_u32*)g, (as3_u32*)l, 16, 0, 0);
#else
    *(bf16x8*)l = *(const bf16x8*)g;  // reg-staged fallback, same addresses
#endif
}

// =========================== bf16x3 MFMA GEMM ================================
// C = alpha*A@Bt^T (+epilogue).  A: [M][K] split pair. Bt: [N][K] split pair.
// EPI: 0 none | 1 +bias | 2 gelu_exact(+bias) | 3 +bias+resid
// OUT: 0 fp32 C | 1 split pair (hi/lo) | 2 split pair transposed (V: [4][1024][2048])
// CAUSAL: 0 none | 1 skip tiles colStart>=rowStart+128 | 2 K limited to rowStart+128
constexpr int BMt = 128, BNt = 128, BKt = 32;

template <int CAUSAL, int EPI, int OUT>
__global__ __launch_bounds__(256)
void mfma_gemm(const u16* __restrict__ Ah, const u16* __restrict__ Al,
               const u16* __restrict__ Bh, const u16* __restrict__ Bl,
               float* __restrict__ Cf, u16* __restrict__ Ch, u16* __restrict__ Cl,
               const float* __restrict__ bias, const float* __restrict__ resid,
               int M, int N, int K, long bA, long bB, long bC, float alpha)
{
    const int z        = blockIdx.z;
    const int rowStart = blockIdx.y * BMt;
    const int colStart = blockIdx.x * BNt;
    if (CAUSAL == 1 && colStart >= rowStart + BMt) return;

    const u16* Ah_ = Ah + bA * z;
    const u16* Al_ = Al + bA * z;
    const u16* Bh_ = Bh + bB * z;
    const u16* Bl_ = Bl + bB * z;

    __shared__ __align__(16) u16 AsH[128][32];
    __shared__ __align__(16) u16 AsL[128][32];
    __shared__ __align__(16) u16 BsH[128][32];
    __shared__ __align__(16) u16 BsL[128][32];

    const int tid = threadIdx.x;
    const int l   = tid & 63;
    const int w   = tid >> 6;           // wave 0..3
    const int wr  = w >> 1, wc = w & 1; // 2x2 wave grid, 64x64 per wave
    const int fr  = l & 15;             // fragment row (A) / col (B) index
    const int fk  = (l >> 4) * 8;       // k-offset within BK=32 (8 contiguous)

    const f32x4 fz = {0.f, 0.f, 0.f, 0.f};
    f32x4 acc[4][4];
#pragma unroll
    for (int m = 0; m < 4; ++m)
#pragma unroll
        for (int n = 0; n < 4; ++n) acc[m][n] = fz;

    int kTiles = K / BKt;
    if (CAUSAL == 2) {
        int kEnd = rowStart + BMt;       // == round128(i+1) for every row in block
        if (kEnd > K) kEnd = K;
        kTiles = kEnd / BKt;
    }

    for (int t = 0; t < kTiles; ++t) {
        const int kb = t * BKt;
#pragma unroll
        for (int s = 0; s < 2; ++s) {
            int gg = s * 256 + tid;          // 16B granule id (512 per tile)
            int r  = gg >> 2;                // tile row 0..127
            int ko = (gg & 3) * 8;           // k elem offset 0/8/16/24
            size_t aoff = (size_t)(rowStart + r) * K + kb + ko;
            size_t boff = (size_t)(colStart + r) * K + kb + ko;
            gld_lds16(Ah_ + aoff, &AsH[0][0] + (size_t)gg * 8);
            gld_lds16(Al_ + aoff, &AsL[0][0] + (size_t)gg * 8);
            gld_lds16(Bh_ + boff, &BsH[0][0] + (size_t)gg * 8);
            gld_lds16(Bl_ + boff, &BsL[0][0] + (size_t)gg * 8);
        }
        __syncthreads();  // compiler drains vmcnt before barrier -> tiles ready

        bf16x8 aH[4], aL[4], bH[4], bL[4];
#pragma unroll
        for (int m = 0; m < 4; ++m) {
            aH[m] = *(const bf16x8*)&AsH[wr * 64 + m * 16 + fr][fk];
            aL[m] = *(const bf16x8*)&AsL[wr * 64 + m * 16 + fr][fk];
        }
#pragma unroll
        for (int n = 0; n < 4; ++n) {
            bH[n] = *(const bf16x8*)&BsH[wc * 64 + n * 16 + fr][fk];
            bL[n] = *(const bf16x8*)&BsL[wc * 64 + n * 16 + fr][fk];
        }
#pragma unroll
        for (int m = 0; m < 4; ++m)
#pragma unroll
            for (int n = 0; n < 4; ++n) {
                acc[m][n] = __builtin_amdgcn_mfma_f32_16x16x32_bf16(aH[m], bH[n], acc[m][n], 0, 0, 0);
                acc[m][n] = __builtin_amdgcn_mfma_f32_16x16x32_bf16(aH[m], bL[n], acc[m][n], 0, 0, 0);
                acc[m][n] = __builtin_amdgcn_mfma_f32_16x16x32_bf16(aL[m], bH[n], acc[m][n], 0, 0, 0);
            }
        __syncthreads();
    }

    // -------- epilogue: C/D mapping col=lane&15, row=(lane>>4)*4+reg ---------
#pragma unroll
    for (int m = 0; m < 4; ++m) {
#pragma unroll
        for (int n = 0; n < 4; ++n) {
            const int col = colStart + wc * 64 + n * 16 + fr;
            float bv = 0.f;
            if (EPI >= 1) bv = bias[col];
#pragma unroll
            for (int r = 0; r < 4; ++r) {
                const int row = rowStart + wr * 64 + m * 16 + (l >> 4) * 4 + r;
                float v = acc[m][n][r] * alpha;
                if (EPI >= 1) v += bv;
                if (EPI == 2) v = 0.5f * v * (1.0f + erff(v * 0.70710678118654752f));
                if (EPI == 3) v += resid[(size_t)row * N + col];
                if (OUT == 0) {
                    Cf[bC * z + (size_t)row * N + col] = v;
                } else if (OUT == 1) {
                    size_t o = bC * z + (size_t)row * N + col;
                    u16 h = f2bf(v);
                    Ch[o] = h;
                    Cl[o] = f2bf(v - bf2f(h));
                } else { // OUT==2: V projection -> Vt [4][1024][2048]
                    int b = row >> 11, tt = row & (SEQ_ - 1);
                    size_t o = ((size_t)b << 21) + ((size_t)col << 11) + tt;
                    u16 h = f2bf(v);
                    Ch[o] = h;
                    Cl[o] = f2bf(v - bf2f(h));
                }
            }
        }
    }
}

// ======================= prep: split / transpose-split =======================
__global__ __launch_bounds__(256)
void split_f32(const float* __restrict__ in, u16* __restrict__ oh, u16* __restrict__ ol, long n4)
{
    long i  = (long)blockIdx.x * 256 + threadIdx.x;
    long st = (long)gridDim.x * 256;
    for (; i < n4; i += st) {
        float4 v = ((const float4*)in)[i];
        ushort4 h, lo;
        h.x = f2bf(v.x); lo.x = f2bf(v.x - bf2f(h.x));
        h.y = f2bf(v.y); lo.y = f2bf(v.y - bf2f(h.y));
        h.z = f2bf(v.z); lo.z = f2bf(v.z - bf2f(h.z));
        h.w = f2bf(v.w); lo.w = f2bf(v.w - bf2f(h.w));
        ((ushort4*)oh)[i] = h;
        ((ushort4*)ol)[i] = lo;
    }
}

// in [R][C] fp32 -> out [C][R] split pair
__global__ __launch_bounds__(256)
void transpose_split(const float* __restrict__ in, u16* __restrict__ oh, u16* __restrict__ ol,
                     int R, int C)
{
    __shared__ float t[32][33];
    const int c0 = blockIdx.x * 32, r0 = blockIdx.y * 32;
    const int tx = threadIdx.x, ty = threadIdx.y; // block (32,8)
#pragma unroll
    for (int s = 0; s < 4; ++s)
        t[ty + s * 8][tx] = in[(size_t)(r0 + ty + s * 8) * C + c0 + tx];
    __syncthreads();
#pragma unroll
    for (int s = 0; s < 4; ++s) {
        int cl = ty + s * 8;
        float v = t[tx][cl];
        size_t o = (size_t)(c0 + cl) * R + r0 + tx;
        u16 h = f2bf(v);
        oh[o] = h;
        ol[o] = f2bf(v - bf2f(h));
    }
}

// ============== causal softmax, in place on split score arrays ===============
__global__ __launch_bounds__(256)
void softmax_split(u16* __restrict__ hi, u16* __restrict__ lo)
{
    const int row = blockIdx.x;             // 0..8191
    const int b   = row >> 11;
    const int i   = row & (SEQ_ - 1);
    u16* ph = hi + ((size_t)b * SEQ_ + i) * SEQ_;
    u16* pl = lo + ((size_t)b * SEQ_ + i) * SEQ_;
    const int len = i + 1;
    const int lenPad = (len + 127) & ~127;  // == PV's causal k-limit for this row
    const int tid = threadIdx.x;
    __shared__ float buf[SEQ_];
    __shared__ float red[256];

    float m = -INFINITY;
    for (int j = tid; j < len; j += 256) {
        float s = bf2f(ph[j]) + bf2f(pl[j]);
        buf[j] = s;
        m = fmaxf(m, s);
    }
    red[tid] = m; __syncthreads();
    for (int o = 128; o > 0; o >>= 1) { if (tid < o) red[tid] = fmaxf(red[tid], red[tid + o]); __syncthreads(); }
    m = red[0]; __syncthreads();

    float sum = 0.f;
    for (int j = tid; j < len; j += 256) { float e = expf(buf[j] - m); buf[j] = e; sum += e; }
    red[tid] = sum; __syncthreads();
    for (int o = 128; o > 0; o >>= 1) { if (tid < o) red[tid] += red[tid + o]; __syncthreads(); }
    const float inv = 1.0f / red[0];

    for (int j = tid; j < len; j += 256) {
        float p = buf[j] * inv;
        u16 h = f2bf(p);
        ph[j] = h;
        pl[j] = f2bf(p - bf2f(h));
    }
    for (int j = len + tid; j < lenPad; j += 256) { ph[j] = 0; pl[j] = 0; }
}

// ============ fused residual + LayerNorm (+ optional split output) ===========
__global__ __launch_bounds__(256)
void ln_kernel(const float* __restrict__ a, const float* __restrict__ r,
               const float* __restrict__ g, const float* __restrict__ beta,
               float* __restrict__ out, u16* __restrict__ oh, u16* __restrict__ ol)
{
    const int row = blockIdx.x, tid = threadIdx.x;
    float4 v = ((const float4*)(a + (size_t)row * D_MODEL))[tid];
    if (r) {
        float4 wv = ((const float4*)(r + (size_t)row * D_MODEL))[tid];
        v.x += wv.x; v.y += wv.y; v.z += wv.z; v.w += wv.w;
    }
    __shared__ float red[256];
    red[tid] = v.x + v.y + v.z + v.w; __syncthreads();
    for (int o = 128; o > 0; o >>= 1) { if (tid < o) red[tid] += red[tid + o]; __syncthreads(); }
    const float mu = red[0] * (1.0f / D_MODEL);
    __syncthreads();
    const float dx = v.x - mu, dy = v.y - mu, dz = v.z - mu, dw = v.w - mu;
    red[tid] = dx * dx + dy * dy + dz * dz + dw * dw; __syncthreads();
    for (int o = 128; o > 0; o >>= 1) { if (tid < o) red[tid] += red[tid + o]; __syncthreads(); }
    const float rs = rsqrtf(red[0] * (1.0f / D_MODEL) + 1e-5f);
    const float4 gv = ((const float4*)g)[tid];
    const float4 bv = ((const float4*)beta)[tid];
    float4 o4 = make_float4(dx * rs * gv.x + bv.x, dy * rs * gv.y + bv.y,
                            dz * rs * gv.z + bv.z, dw * rs * gv.w + bv.w);
    ((float4*)(out + (size_t)row * D_MODEL))[tid] = o4;
    if (oh) {
        ushort4 h, lo;
        h.x = f2bf(o4.x); lo.x = f2bf(o4.x - bf2f(h.x));
        h.y = f2bf(o4.y); lo.y = f2bf(o4.y - bf2f(h.y));
        h.z = f2bf(o4.z); lo.z = f2bf(o4.z - bf2f(h.z));
        h.w = f2bf(o4.w); lo.w = f2bf(o4.w - bf2f(h.w));
        ((ushort4*)(oh + (size_t)row * D_MODEL))[tid] = h;
        ((ushort4*)(ol + (size_t)row * D_MODEL))[tid] = lo;
    }
}

// ================================ launch =====================================
// Workspace arena (MB offsets), lifetime-overlapped; peak 204 MB:
//   [0,12)    WqT/WkT/WvT splits (2 MB each)
//   [12,44)   xs split -> attn fp32 (after QKV) -> W1T/W2T splits (after LN1)
//   [44,76)   Qs split -> hs split (after scores GEMM)
//   [76,108)  Ks split ┐
//   [108,140) Vt split ├-> fh/fl [76,204) (after PV+LN1)
//   [140,204) Ss split ┘
extern "C" void kernel_launch(void* const* d_in, const int* in_sizes, int n_in,
                              void* d_out, int out_size, void* d_ws, size_t ws_size,
                              hipStream_t stream)
{
    const float* x    = (const float*)d_in[0];
    const float* Wq   = (const float*)d_in[1];
    const float* Wk   = (const float*)d_in[2];
    const float* Wv   = (const float*)d_in[3];
    const float* ln1g = (const float*)d_in[4];
    const float* ln1b = (const float*)d_in[5];
    const float* ln2g = (const float*)d_in[6];
    const float* ln2b = (const float*)d_in[7];
    const float* W1   = (const float*)d_in[8];
    const float* b1   = (const float*)d_in[9];
    const float* W2   = (const float*)d_in[10];
    const float* b2   = (const float*)d_in[11];

    const int Mrows = NBATCH * SEQ_; // 8192

    char* wsb = (char*)d_ws;
    auto U = [&](size_t mb) { return (u16*)(wsb + mb * (size_t)(1 << 20)); };
    u16 *WqTh = U(0),   *WqTl = U(2);
    u16 *WkTh = U(4),   *WkTl = U(6);
    u16 *WvTh = U(8),   *WvTl = U(10);
    u16 *xsh  = U(12),  *xsl  = U(28);    // [8192][1024] split
    float* attn = (float*)(wsb + 12 * (size_t)(1 << 20)); // fp32, reuses xs
    u16 *W1Th = U(12),  *W1Tl = U(20);    // [4096][1024] split, after LN1
    u16 *W2Th = U(28),  *W2Tl = U(36);    // [1024][4096] split, after LN1
    u16 *Qsh  = U(44),  *Qsl  = U(60);
    u16 *hsh  = U(44),  *hsl  = U(60);    // reuses Qs (dead after scores)
    u16 *Ksh  = U(76),  *Ksl  = U(92);
    u16 *Vth  = U(108), *Vtl  = U(124);   // V^T split [4][1024][2048]
    u16 *Ssh  = U(140), *Ssl  = U(172);   // scores/P split [4][2048][2048]
    u16 *fh   = U(76),  *fl   = U(140);   // ffh split [8192][4096], reuses Ks/Vt/Ss
    float* h  = (float*)d_out;            // h fp32 lives in d_out until FFN2

    dim3 b256(256), tb(32, 8);

    // QKV weight transpose+split, x split
    transpose_split<<<dim3(32, 32), tb, 0, stream>>>(Wq, WqTh, WqTl, 1024, 1024);
    transpose_split<<<dim3(32, 32), tb, 0, stream>>>(Wk, WkTh, WkTl, 1024, 1024);
    transpose_split<<<dim3(32, 32), tb, 0, stream>>>(Wv, WvTh, WvTl, 1024, 1024);
    split_f32<<<dim3(2048), b256, 0, stream>>>(x, xsh, xsl, (long)Mrows * D_MODEL / 4);

    // Q/K/V projections (split outputs; V transposed)
    mfma_gemm<0, 0, 1><<<dim3(8, 64, 1), b256, 0, stream>>>(
        xsh, xsl, WqTh, WqTl, nullptr, Qsh, Qsl, nullptr, nullptr,
        Mrows, D_MODEL, D_MODEL, 0, 0, 0, 1.f);
    mfma_gemm<0, 0, 1><<<dim3(8, 64, 1), b256, 0, stream>>>(
        xsh, xsl, WkTh, WkTl, nullptr, Ksh, Ksl, nullptr, nullptr,
        Mrows, D_MODEL, D_MODEL, 0, 0, 0, 1.f);
    mfma_gemm<0, 0, 2><<<dim3(8, 64, 1), b256, 0, stream>>>(
        xsh, xsl, WvTh, WvTl, nullptr, Vth, Vtl, nullptr, nullptr,
        Mrows, D_MODEL, D_MODEL, 0, 0, 0, 1.f);

    // scores = Q@K^T/32 (causal tiles only) -> split, then softmax in place
    mfma_gemm<1, 0, 1><<<dim3(16, 16, NBATCH), b256, 0, stream>>>(
        Qsh, Qsl, Ksh, Ksl, nullptr, Ssh, Ssl, nullptr, nullptr,
        SEQ_, SEQ_, D_MODEL, (long)SEQ_ * D_MODEL, (long)SEQ_ * D_MODEL,
        (long)SEQ_ * SEQ_, 0.03125f);
    softmax_split<<<dim3(Mrows), b256, 0, stream>>>(Ssh, Ssl);

    // attn = P@V  (A=P split, Bt=V^T split, K causal-limited) -> fp32
    mfma_gemm<2, 0, 0><<<dim3(8, 16, NBATCH), b256, 0, stream>>>(
        Ssh, Ssl, Vth, Vtl, attn, nullptr, nullptr, nullptr, nullptr,
        SEQ_, D_MODEL, SEQ_, (long)SEQ_ * SEQ_, (long)D_MODEL * SEQ_,
        (long)SEQ_ * D_MODEL, 1.f);

    // h = LN(x + attn) -> fp32 into d_out + split for FFN1
    ln_kernel<<<dim3(Mrows), b256, 0, stream>>>(x, attn, ln1g, ln1b, h, hsh, hsl);

    // FFN weight transpose+split (after LN1: their arena overlaps attn)
    transpose_split<<<dim3(128, 32), tb, 0, stream>>>(W1, W1Th, W1Tl, 1024, 4096);
    transpose_split<<<dim3(32, 128), tb, 0, stream>>>(W2, W2Th, W2Tl, 4096, 1024);

    // ffh = gelu(h@W1+b1) -> split
    mfma_gemm<0, 2, 1><<<dim3(32, 64, 1), b256, 0, stream>>>(
        hsh, hsl, W1Th, W1Tl, nullptr, fh, fl, b1, nullptr,
        Mrows, DFF_, D_MODEL, 0, 0, 0, 1.f);

    // out_pre = ffh@W2 + b2 + h -> fp32 into d_out (same-lane RMW vs resid=h)
    mfma_gemm<0, 3, 0><<<dim3(8, 64, 1), b256, 0, stream>>>(
        fh, fl, W2Th, W2Tl, (float*)d_out, nullptr, nullptr, b2, h,
        Mrows, D_MODEL, DFF_, 0, 0, 0, 1.f);

    // out = LN(out_pre) in place
    ln_kernel<<<dim3(Mrows), b256, 0, stream>>>(
        (const float*)d_out, nullptr, ln2g, ln2b, (float*)d_out, nullptr, nullptr);
}

// Round 5
// 1038.119 us; speedup vs baseline: 1.0036x; 1.0036x over previous
//
#include <hip/hip_runtime.h>
#include <math.h>

// SimpleAttentionBlock fp32 -> bf16x3 split-GEMM on MFMA (gfx950).
// All GEMMs: A[M,K] (hi/lo bf16) x Bt[N,K] (hi/lo bf16) with fp32 MFMA accum,
// 3 products (hh, hl, lh) ~= fp32 accuracy. Round 4/5: + XCD-aware block swizzle
// (stripe-ordered row bands; A-stripe L2-resident, B re-reads L3-served).

#define D_MODEL 1024
#define DFF_    4096
#define SEQ_    2048
#define NBATCH  4

typedef unsigned short u16;
typedef __attribute__((ext_vector_type(8))) short bf16x8;
typedef __attribute__((ext_vector_type(4))) float f32x4;

__device__ __forceinline__ u16 f2bf(float f) {
    unsigned u = __float_as_uint(f);
    unsigned r = (u + 0x7fffu + ((u >> 16) & 1u)) >> 16;
    return (u16)r;
}
__device__ __forceinline__ float bf2f(u16 h) {
    return __uint_as_float(((unsigned)h) << 16);
}

// ---- async 16B global->LDS. LDS dest must be wave-uniform base + lane*16
// (our staging layout satisfies this: lds offset = (s*256+tid)*16).
__device__ __forceinline__ void gld_lds16(const void* g, void* l) {
#if __has_builtin(__builtin_amdgcn_global_load_lds)
    typedef __attribute__((address_space(1))) const unsigned int as1_u32;
    typedef __attribute__((address_space(3))) unsigned int as3_u32;
    __builtin_amdgcn_global_load_lds((as1_u32*)g, (as3_u32*)l, 16, 0, 0);
#else
    *(bf16x8*)l = *(const bf16x8*)g;  // reg-staged fallback, same addresses
#endif
}

// =========================== bf16x3 MFMA GEMM ================================
// C = alpha*A@Bt^T (+epilogue).  A: [M][K] split pair. Bt: [N][K] split pair.
// EPI: 0 none | 1 +bias | 2 gelu_exact(+bias) | 3 +bias+resid
// OUT: 0 fp32 C | 1 split pair (hi/lo) | 2 split pair transposed (V: [4][1024][2048])
// CAUSAL: 0 none | 1 skip tiles colStart>=rowStart+128 | 2 K limited to rowStart+128
// SWZ_HS: 0 = no swizzle | hs = XCD row-band swizzle, stripes of hs row-panels,
//         rows-fastest within stripe (requires gridDim.y%8==0, (GY/8)%hs==0).
constexpr int BMt = 128, BNt = 128, BKt = 32;

template <int CAUSAL, int EPI, int OUT, int SWZ_HS>
__global__ __launch_bounds__(256)
void mfma_gemm(const u16* __restrict__ Ah, const u16* __restrict__ Al,
               const u16* __restrict__ Bh, const u16* __restrict__ Bl,
               float* __restrict__ Cf, u16* __restrict__ Ch, u16* __restrict__ Cl,
               const float* __restrict__ bias, const float* __restrict__ resid,
               int M, int N, int K, long bA, long bB, long bC, float alpha)
{
    const int z = blockIdx.z;
    int bx = blockIdx.x, by = blockIdx.y;
    if (SWZ_HS > 0) {
        // XCD = g&7 (8 XCDs, round-robin dispatch). Each XCD owns GY/8
        // consecutive row-panels; walk them in stripes of hs rows, rows-fastest.
        const int GX = gridDim.x, GY = gridDim.y;
        const int g   = bx + GX * by;
        const int xcd = g & 7;
        const int li  = g >> 3;                 // 0 .. GX*GY/8-1
        const int RB  = GY >> 3;                // row-panels per XCD
        const int r   = li % SWZ_HS;
        const int c   = (li / SWZ_HS) % GX;
        const int s   = li / (SWZ_HS * GX);
        by = xcd * RB + s * SWZ_HS + r;
        bx = c;
    }
    const int rowStart = by * BMt;
    const int colStart = bx * BNt;
    if (CAUSAL == 1 && colStart >= rowStart + BMt) return;

    const u16* Ah_ = Ah + bA * z;
    const u16* Al_ = Al + bA * z;
    const u16* Bh_ = Bh + bB * z;
    const u16* Bl_ = Bl + bB * z;

    __shared__ __align__(16) u16 AsH[128][32];
    __shared__ __align__(16) u16 AsL[128][32];
    __shared__ __align__(16) u16 BsH[128][32];
    __shared__ __align__(16) u16 BsL[128][32];

    const int tid = threadIdx.x;
    const int l   = tid & 63;
    const int w   = tid >> 6;           // wave 0..3
    const int wr  = w >> 1, wc = w & 1; // 2x2 wave grid, 64x64 per wave
    const int fr  = l & 15;             // fragment row (A) / col (B) index
    const int fk  = (l >> 4) * 8;       // k-offset within BK=32 (8 contiguous)

    const f32x4 fz = {0.f, 0.f, 0.f, 0.f};
    f32x4 acc[4][4];
#pragma unroll
    for (int m = 0; m < 4; ++m)
#pragma unroll
        for (int n = 0; n < 4; ++n) acc[m][n] = fz;

    int kTiles = K / BKt;
    if (CAUSAL == 2) {
        int kEnd = rowStart + BMt;       // == round128(i+1) for every row in block
        if (kEnd > K) kEnd = K;
        kTiles = kEnd / BKt;
    }

    for (int t = 0; t < kTiles; ++t) {
        const int kb = t * BKt;
#pragma unroll
        for (int s = 0; s < 2; ++s) {
            int gg = s * 256 + tid;          // 16B granule id (512 per tile)
            int r  = gg >> 2;                // tile row 0..127
            int ko = (gg & 3) * 8;           // k elem offset 0/8/16/24
            size_t aoff = (size_t)(rowStart + r) * K + kb + ko;
            size_t boff = (size_t)(colStart + r) * K + kb + ko;
            gld_lds16(Ah_ + aoff, &AsH[0][0] + (size_t)gg * 8);
            gld_lds16(Al_ + aoff, &AsL[0][0] + (size_t)gg * 8);
            gld_lds16(Bh_ + boff, &BsH[0][0] + (size_t)gg * 8);
            gld_lds16(Bl_ + boff, &BsL[0][0] + (size_t)gg * 8);
        }
        __syncthreads();  // compiler drains vmcnt before barrier -> tiles ready

        bf16x8 aH[4], aL[4], bH[4], bL[4];
#pragma unroll
        for (int m = 0; m < 4; ++m) {
            aH[m] = *(const bf16x8*)&AsH[wr * 64 + m * 16 + fr][fk];
            aL[m] = *(const bf16x8*)&AsL[wr * 64 + m * 16 + fr][fk];
        }
#pragma unroll
        for (int n = 0; n < 4; ++n) {
            bH[n] = *(const bf16x8*)&BsH[wc * 64 + n * 16 + fr][fk];
            bL[n] = *(const bf16x8*)&BsL[wc * 64 + n * 16 + fr][fk];
        }
#pragma unroll
        for (int m = 0; m < 4; ++m)
#pragma unroll
            for (int n = 0; n < 4; ++n) {
                acc[m][n] = __builtin_amdgcn_mfma_f32_16x16x32_bf16(aH[m], bH[n], acc[m][n], 0, 0, 0);
                acc[m][n] = __builtin_amdgcn_mfma_f32_16x16x32_bf16(aH[m], bL[n], acc[m][n], 0, 0, 0);
                acc[m][n] = __builtin_amdgcn_mfma_f32_16x16x32_bf16(aL[m], bH[n], acc[m][n], 0, 0, 0);
            }
        __syncthreads();
    }

    // -------- epilogue: C/D mapping col=lane&15, row=(lane>>4)*4+reg ---------
#pragma unroll
    for (int m = 0; m < 4; ++m) {
#pragma unroll
        for (int n = 0; n < 4; ++n) {
            const int col = colStart + wc * 64 + n * 16 + fr;
            float bv = 0.f;
            if (EPI >= 1) bv = bias[col];
#pragma unroll
            for (int r = 0; r < 4; ++r) {
                const int row = rowStart + wr * 64 + m * 16 + (l >> 4) * 4 + r;
                float v = acc[m][n][r] * alpha;
                if (EPI >= 1) v += bv;
                if (EPI == 2) v = 0.5f * v * (1.0f + erff(v * 0.70710678118654752f));
                if (EPI == 3) v += resid[(size_t)row * N + col];
                if (OUT == 0) {
                    Cf[bC * z + (size_t)row * N + col] = v;
                } else if (OUT == 1) {
                    size_t o = bC * z + (size_t)row * N + col;
                    u16 h = f2bf(v);
                    Ch[o] = h;
                    Cl[o] = f2bf(v - bf2f(h));
                } else { // OUT==2: V projection -> Vt [4][1024][2048]
                    int b = row >> 11, tt = row & (SEQ_ - 1);
                    size_t o = ((size_t)b << 21) + ((size_t)col << 11) + tt;
                    u16 h = f2bf(v);
                    Ch[o] = h;
                    Cl[o] = f2bf(v - bf2f(h));
                }
            }
        }
    }
}

// ======================= prep: split / transpose-split =======================
__global__ __launch_bounds__(256)
void split_f32(const float* __restrict__ in, u16* __restrict__ oh, u16* __restrict__ ol, long n4)
{
    long i  = (long)blockIdx.x * 256 + threadIdx.x;
    long st = (long)gridDim.x * 256;
    for (; i < n4; i += st) {
        float4 v = ((const float4*)in)[i];
        ushort4 h, lo;
        h.x = f2bf(v.x); lo.x = f2bf(v.x - bf2f(h.x));
        h.y = f2bf(v.y); lo.y = f2bf(v.y - bf2f(h.y));
        h.z = f2bf(v.z); lo.z = f2bf(v.z - bf2f(h.z));
        h.w = f2bf(v.w); lo.w = f2bf(v.w - bf2f(h.w));
        ((ushort4*)oh)[i] = h;
        ((ushort4*)ol)[i] = lo;
    }
}

// in [R][C] fp32 -> out [C][R] split pair
__global__ __launch_bounds__(256)
void transpose_split(const float* __restrict__ in, u16* __restrict__ oh, u16* __restrict__ ol,
                     int R, int C)
{
    __shared__ float t[32][33];
    const int c0 = blockIdx.x * 32, r0 = blockIdx.y * 32;
    const int tx = threadIdx.x, ty = threadIdx.y; // block (32,8)
#pragma unroll
    for (int s = 0; s < 4; ++s)
        t[ty + s * 8][tx] = in[(size_t)(r0 + ty + s * 8) * C + c0 + tx];
    __syncthreads();
#pragma unroll
    for (int s = 0; s < 4; ++s) {
        int cl = ty + s * 8;
        float v = t[tx][cl];
        size_t o = (size_t)(c0 + cl) * R + r0 + tx;
        u16 h = f2bf(v);
        oh[o] = h;
        ol[o] = f2bf(v - bf2f(h));
    }
}

// ============== causal softmax, in place on split score arrays ===============
__global__ __launch_bounds__(256)
void softmax_split(u16* __restrict__ hi, u16* __restrict__ lo)
{
    const int row = blockIdx.x;             // 0..8191
    const int b   = row >> 11;
    const int i   = row & (SEQ_ - 1);
    u16* ph = hi + ((size_t)b * SEQ_ + i) * SEQ_;
    u16* pl = lo + ((size_t)b * SEQ_ + i) * SEQ_;
    const int len = i + 1;
    const int lenPad = (len + 127) & ~127;  // == PV's causal k-limit for this row
    const int tid = threadIdx.x;
    __shared__ float buf[SEQ_];
    __shared__ float red[256];

    float m = -INFINITY;
    for (int j = tid; j < len; j += 256) {
        float s = bf2f(ph[j]) + bf2f(pl[j]);
        buf[j] = s;
        m = fmaxf(m, s);
    }
    red[tid] = m; __syncthreads();
    for (int o = 128; o > 0; o >>= 1) { if (tid < o) red[tid] = fmaxf(red[tid], red[tid + o]); __syncthreads(); }
    m = red[0]; __syncthreads();

    float sum = 0.f;
    for (int j = tid; j < len; j += 256) { float e = expf(buf[j] - m); buf[j] = e; sum += e; }
    red[tid] = sum; __syncthreads();
    for (int o = 128; o > 0; o >>= 1) { if (tid < o) red[tid] += red[tid + o]; __syncthreads(); }
    const float inv = 1.0f / red[0];

    for (int j = tid; j < len; j += 256) {
        float p = buf[j] * inv;
        u16 h = f2bf(p);
        ph[j] = h;
        pl[j] = f2bf(p - bf2f(h));
    }
    for (int j = len + tid; j < lenPad; j += 256) { ph[j] = 0; pl[j] = 0; }
}

// ============ fused residual + LayerNorm (+ optional split output) ===========
__global__ __launch_bounds__(256)
void ln_kernel(const float* __restrict__ a, const float* __restrict__ r,
               const float* __restrict__ g, const float* __restrict__ beta,
               float* __restrict__ out, u16* __restrict__ oh, u16* __restrict__ ol)
{
    const int row = blockIdx.x, tid = threadIdx.x;
    float4 v = ((const float4*)(a + (size_t)row * D_MODEL))[tid];
    if (r) {
        float4 wv = ((const float4*)(r + (size_t)row * D_MODEL))[tid];
        v.x += wv.x; v.y += wv.y; v.z += wv.z; v.w += wv.w;
    }
    __shared__ float red[256];
    red[tid] = v.x + v.y + v.z + v.w; __syncthreads();
    for (int o = 128; o > 0; o >>= 1) { if (tid < o) red[tid] += red[tid + o]; __syncthreads(); }
    const float mu = red[0] * (1.0f / D_MODEL);
    __syncthreads();
    const float dx = v.x - mu, dy = v.y - mu, dz = v.z - mu, dw = v.w - mu;
    red[tid] = dx * dx + dy * dy + dz * dz + dw * dw; __syncthreads();
    for (int o = 128; o > 0; o >>= 1) { if (tid < o) red[tid] += red[tid + o]; __syncthreads(); }
    const float rs = rsqrtf(red[0] * (1.0f / D_MODEL) + 1e-5f);
    const float4 gv = ((const float4*)g)[tid];
    const float4 bv = ((const float4*)beta)[tid];
    float4 o4 = make_float4(dx * rs * gv.x + bv.x, dy * rs * gv.y + bv.y,
                            dz * rs * gv.z + bv.z, dw * rs * gv.w + bv.w);
    ((float4*)(out + (size_t)row * D_MODEL))[tid] = o4;
    if (oh) {
        ushort4 h, lo;
        h.x = f2bf(o4.x); lo.x = f2bf(o4.x - bf2f(h.x));
        h.y = f2bf(o4.y); lo.y = f2bf(o4.y - bf2f(h.y));
        h.z = f2bf(o4.z); lo.z = f2bf(o4.z - bf2f(h.z));
        h.w = f2bf(o4.w); lo.w = f2bf(o4.w - bf2f(h.w));
        ((ushort4*)(oh + (size_t)row * D_MODEL))[tid] = h;
        ((ushort4*)(ol + (size_t)row * D_MODEL))[tid] = lo;
    }
}

// ================================ launch =====================================
// Workspace arena (MB offsets), lifetime-overlapped; peak 204 MB:
//   [0,12)    WqT/WkT/WvT splits (2 MB each)
//   [12,44)   xs split -> attn fp32 (after QKV) -> W1T/W2T splits (after LN1)
//   [44,76)   Qs split -> hs split (after scores GEMM)
//   [76,108)  Ks split ┐
//   [108,140) Vt split ├-> fh/fl [76,204) (after PV+LN1)
//   [140,204) Ss split ┘
extern "C" void kernel_launch(void* const* d_in, const int* in_sizes, int n_in,
                              void* d_out, int out_size, void* d_ws, size_t ws_size,
                              hipStream_t stream)
{
    const float* x    = (const float*)d_in[0];
    const float* Wq   = (const float*)d_in[1];
    const float* Wk   = (const float*)d_in[2];
    const float* Wv   = (const float*)d_in[3];
    const float* ln1g = (const float*)d_in[4];
    const float* ln1b = (const float*)d_in[5];
    const float* ln2g = (const float*)d_in[6];
    const float* ln2b = (const float*)d_in[7];
    const float* W1   = (const float*)d_in[8];
    const float* b1   = (const float*)d_in[9];
    const float* W2   = (const float*)d_in[10];
    const float* b2   = (const float*)d_in[11];

    const int Mrows = NBATCH * SEQ_; // 8192

    char* wsb = (char*)d_ws;
    auto U = [&](size_t mb) { return (u16*)(wsb + mb * (size_t)(1 << 20)); };
    u16 *WqTh = U(0),   *WqTl = U(2);
    u16 *WkTh = U(4),   *WkTl = U(6);
    u16 *WvTh = U(8),   *WvTl = U(10);
    u16 *xsh  = U(12),  *xsl  = U(28);    // [8192][1024] split
    float* attn = (float*)(wsb + 12 * (size_t)(1 << 20)); // fp32, reuses xs
    u16 *W1Th = U(12),  *W1Tl = U(20);    // [4096][1024] split, after LN1
    u16 *W2Th = U(28),  *W2Tl = U(36);    // [1024][4096] split, after LN1
    u16 *Qsh  = U(44),  *Qsl  = U(60);
    u16 *hsh  = U(44),  *hsl  = U(60);    // reuses Qs (dead after scores)
    u16 *Ksh  = U(76),  *Ksl  = U(92);
    u16 *Vth  = U(108), *Vtl  = U(124);   // V^T split [4][1024][2048]
    u16 *Ssh  = U(140), *Ssl  = U(172);   // scores/P split [4][2048][2048]
    u16 *fh   = U(76),  *fl   = U(140);   // ffh split [8192][4096], reuses Ks/Vt/Ss
    float* h  = (float*)d_out;            // h fp32 lives in d_out until FFN2

    dim3 b256(256), tb(32, 8);

    // QKV weight transpose+split, x split
    transpose_split<<<dim3(32, 32), tb, 0, stream>>>(Wq, WqTh, WqTl, 1024, 1024);
    transpose_split<<<dim3(32, 32), tb, 0, stream>>>(Wk, WkTh, WkTl, 1024, 1024);
    transpose_split<<<dim3(32, 32), tb, 0, stream>>>(Wv, WvTh, WvTl, 1024, 1024);
    split_f32<<<dim3(2048), b256, 0, stream>>>(x, xsh, xsl, (long)Mrows * D_MODEL / 4);

    // Q/K/V projections (split outputs; V transposed). SWZ hs=4 (K=1024).
    mfma_gemm<0, 0, 1, 4><<<dim3(8, 64, 1), b256, 0, stream>>>(
        xsh, xsl, WqTh, WqTl, nullptr, Qsh, Qsl, nullptr, nullptr,
        Mrows, D_MODEL, D_MODEL, 0, 0, 0, 1.f);
    mfma_gemm<0, 0, 1, 4><<<dim3(8, 64, 1), b256, 0, stream>>>(
        xsh, xsl, WkTh, WkTl, nullptr, Ksh, Ksl, nullptr, nullptr,
        Mrows, D_MODEL, D_MODEL, 0, 0, 0, 1.f);
    mfma_gemm<0, 0, 2, 4><<<dim3(8, 64, 1), b256, 0, stream>>>(
        xsh, xsl, WvTh, WvTl, nullptr, Vth, Vtl, nullptr, nullptr,
        Mrows, D_MODEL, D_MODEL, 0, 0, 0, 1.f);

    // scores = Q@K^T/32 (causal tiles only) -> split, then softmax in place.
    // No swizzle: causal tile-skip makes row-band XCD mapping imbalanced.
    mfma_gemm<1, 0, 1, 0><<<dim3(16, 16, NBATCH), b256, 0, stream>>>(
        Qsh, Qsl, Ksh, Ksl, nullptr, Ssh, Ssl, nullptr, nullptr,
        SEQ_, SEQ_, D_MODEL, (long)SEQ_ * D_MODEL, (long)SEQ_ * D_MODEL,
        (long)SEQ_ * SEQ_, 0.03125f);
    softmax_split<<<dim3(Mrows), b256, 0, stream>>>(Ssh, Ssl);

    // attn = P@V  (A=P split, Bt=V^T split, K causal-limited) -> fp32
    mfma_gemm<2, 0, 0, 0><<<dim3(8, 16, NBATCH), b256, 0, stream>>>(
        Ssh, Ssl, Vth, Vtl, attn, nullptr, nullptr, nullptr, nullptr,
        SEQ_, D_MODEL, SEQ_, (long)SEQ_ * SEQ_, (long)D_MODEL * SEQ_,
        (long)SEQ_ * D_MODEL, 1.f);

    // h = LN(x + attn) -> fp32 into d_out + split for FFN1
    ln_kernel<<<dim3(Mrows), b256, 0, stream>>>(x, attn, ln1g, ln1b, h, hsh, hsl);

    // FFN weight transpose+split (after LN1: their arena overlaps attn)
    transpose_split<<<dim3(128, 32), tb, 0, stream>>>(W1, W1Th, W1Tl, 1024, 4096);
    transpose_split<<<dim3(32, 128), tb, 0, stream>>>(W2, W2Th, W2Tl, 4096, 1024);

    // ffh = gelu(h@W1+b1) -> split. SWZ hs=4 (K=1024, stripe 2.5MB < L2).
    mfma_gemm<0, 2, 1, 4><<<dim3(32, 64, 1), b256, 0, stream>>>(
        hsh, hsl, W1Th, W1Tl, nullptr, fh, fl, b1, nullptr,
        Mrows, DFF_, D_MODEL, 0, 0, 0, 1.f);

    // out_pre = ffh@W2 + b2 + h -> fp32 into d_out. SWZ hs=1 (K=4096: A-panel
    // 2MB stays L2-resident across its 8 col-blocks; ffh fetched once/XCD).
    mfma_gemm<0, 3, 0, 1><<<dim3(8, 64, 1), b256, 0, stream>>>(
        fh, fl, W2Th, W2Tl, (float*)d_out, nullptr, nullptr, b2, h,
        Mrows, D_MODEL, DFF_, 0, 0, 0, 1.f);

    // out = LN(out_pre) in place
    ln_kernel<<<dim3(Mrows), b256, 0, stream>>>(
        (const float*)d_out, nullptr, ln2g, ln2b, (float*)d_out, nullptr, nullptr);
}

// Round 7
// 949.850 us; speedup vs baseline: 1.0969x; 1.0929x over previous
//
#include <hip/hip_runtime.h>
#include <math.h>

// SimpleAttentionBlock fp32 -> bf16x3 split-GEMM on MFMA (gfx950).
// Round 7: same as round 6 with the V-projection launch fixed (was OUT=0 with
// Cf=nullptr -> null-pointer store -> HSA abort). Non-causal GEMMs on the
// 128x256 8-wave phase-split pipeline (3 LDS buffers, depth-2 staging,
// counted vmcnt(6), chunk-XOR LDS swizzle, setprio around MFMA clusters).
// Causal scores/PV keep the proven 128x128 2-barrier kernel.

#define D_MODEL 1024
#define DFF_    4096
#define SEQ_    2048
#define NBATCH  4

typedef unsigned short u16;
typedef __attribute__((ext_vector_type(8))) short bf16x8;
typedef __attribute__((ext_vector_type(4))) float f32x4;

__device__ __forceinline__ u16 f2bf(float f) {
    unsigned u = __float_as_uint(f);
    unsigned r = (u + 0x7fffu + ((u >> 16) & 1u)) >> 16;
    return (u16)r;
}
__device__ __forceinline__ float bf2f(u16 h) {
    return __uint_as_float(((unsigned)h) << 16);
}

// ---- async 16B global->LDS. LDS dest: wave-uniform base + lane*16.
__device__ __forceinline__ void gld_lds16(const void* g, void* l) {
#if __has_builtin(__builtin_amdgcn_global_load_lds)
    typedef __attribute__((address_space(1))) const unsigned int as1_u32;
    typedef __attribute__((address_space(3))) unsigned int as3_u32;
    __builtin_amdgcn_global_load_lds((as1_u32*)g, (as3_u32*)l, 16, 0, 0);
#else
    *(bf16x8*)l = *(const bf16x8*)g;
#endif
}

// ================= 128x128 2-barrier kernel (causal scores/PV) ==============
constexpr int BMt = 128, BNt = 128, BKt = 32;

template <int CAUSAL, int EPI, int OUT, int SWZ_HS>
__global__ __launch_bounds__(256)
void mfma_gemm(const u16* __restrict__ Ah, const u16* __restrict__ Al,
               const u16* __restrict__ Bh, const u16* __restrict__ Bl,
               float* __restrict__ Cf, u16* __restrict__ Ch, u16* __restrict__ Cl,
               const float* __restrict__ bias, const float* __restrict__ resid,
               int M, int N, int K, long bA, long bB, long bC, float alpha)
{
    const int z = blockIdx.z;
    int bx = blockIdx.x, by = blockIdx.y;
    if (SWZ_HS > 0) {
        const int GX = gridDim.x, GY = gridDim.y;
        const int g   = bx + GX * by;
        const int xcd = g & 7;
        const int li  = g >> 3;
        const int RB  = GY >> 3;
        const int rr_ = li % SWZ_HS;
        const int cc_ = (li / SWZ_HS) % GX;
        const int ss_ = li / (SWZ_HS * GX);
        by = xcd * RB + ss_ * SWZ_HS + rr_;
        bx = cc_;
    }
    const int rowStart = by * BMt;
    const int colStart = bx * BNt;
    if (CAUSAL == 1 && colStart >= rowStart + BMt) return;

    const u16* Ah_ = Ah + bA * z;
    const u16* Al_ = Al + bA * z;
    const u16* Bh_ = Bh + bB * z;
    const u16* Bl_ = Bl + bB * z;

    __shared__ __align__(16) u16 AsH[128][32];
    __shared__ __align__(16) u16 AsL[128][32];
    __shared__ __align__(16) u16 BsH[128][32];
    __shared__ __align__(16) u16 BsL[128][32];

    const int tid = threadIdx.x;
    const int l   = tid & 63;
    const int w   = tid >> 6;
    const int wr  = w >> 1, wc = w & 1;
    const int fr  = l & 15;
    const int fk  = (l >> 4) * 8;

    const f32x4 fz = {0.f, 0.f, 0.f, 0.f};
    f32x4 acc[4][4];
#pragma unroll
    for (int m = 0; m < 4; ++m)
#pragma unroll
        for (int n = 0; n < 4; ++n) acc[m][n] = fz;

    int kTiles = K / BKt;
    if (CAUSAL == 2) {
        int kEnd = rowStart + BMt;
        if (kEnd > K) kEnd = K;
        kTiles = kEnd / BKt;
    }

    for (int t = 0; t < kTiles; ++t) {
        const int kb = t * BKt;
#pragma unroll
        for (int s = 0; s < 2; ++s) {
            int gg = s * 256 + tid;
            int r  = gg >> 2;
            int ko = (gg & 3) * 8;
            size_t aoff = (size_t)(rowStart + r) * K + kb + ko;
            size_t boff = (size_t)(colStart + r) * K + kb + ko;
            gld_lds16(Ah_ + aoff, &AsH[0][0] + (size_t)gg * 8);
            gld_lds16(Al_ + aoff, &AsL[0][0] + (size_t)gg * 8);
            gld_lds16(Bh_ + boff, &BsH[0][0] + (size_t)gg * 8);
            gld_lds16(Bl_ + boff, &BsL[0][0] + (size_t)gg * 8);
        }
        __syncthreads();

        bf16x8 aH[4], aL[4], bH[4], bL[4];
#pragma unroll
        for (int m = 0; m < 4; ++m) {
            aH[m] = *(const bf16x8*)&AsH[wr * 64 + m * 16 + fr][fk];
            aL[m] = *(const bf16x8*)&AsL[wr * 64 + m * 16 + fr][fk];
        }
#pragma unroll
        for (int n = 0; n < 4; ++n) {
            bH[n] = *(const bf16x8*)&BsH[wc * 64 + n * 16 + fr][fk];
            bL[n] = *(const bf16x8*)&BsL[wc * 64 + n * 16 + fr][fk];
        }
#pragma unroll
        for (int m = 0; m < 4; ++m)
#pragma unroll
            for (int n = 0; n < 4; ++n) {
                acc[m][n] = __builtin_amdgcn_mfma_f32_16x16x32_bf16(aH[m], bH[n], acc[m][n], 0, 0, 0);
                acc[m][n] = __builtin_amdgcn_mfma_f32_16x16x32_bf16(aH[m], bL[n], acc[m][n], 0, 0, 0);
                acc[m][n] = __builtin_amdgcn_mfma_f32_16x16x32_bf16(aL[m], bH[n], acc[m][n], 0, 0, 0);
            }
        __syncthreads();
    }

#pragma unroll
    for (int m = 0; m < 4; ++m) {
#pragma unroll
        for (int n = 0; n < 4; ++n) {
            const int col = colStart + wc * 64 + n * 16 + fr;
            float bv = 0.f;
            if (EPI >= 1) bv = bias[col];
#pragma unroll
            for (int r = 0; r < 4; ++r) {
                const int row = rowStart + wr * 64 + m * 16 + (l >> 4) * 4 + r;
                float v = acc[m][n][r] * alpha;
                if (EPI >= 1) v += bv;
                if (EPI == 2) v = 0.5f * v * (1.0f + erff(v * 0.70710678118654752f));
                if (EPI == 3) v += resid[(size_t)row * N + col];
                if (OUT == 0) {
                    Cf[bC * z + (size_t)row * N + col] = v;
                } else if (OUT == 1) {
                    size_t o = bC * z + (size_t)row * N + col;
                    u16 h = f2bf(v);
                    Ch[o] = h;
                    Cl[o] = f2bf(v - bf2f(h));
                } else {
                    int b = row >> 11, tt = row & (SEQ_ - 1);
                    size_t o = ((size_t)b << 21) + ((size_t)col << 11) + tt;
                    u16 h = f2bf(v);
                    Ch[o] = h;
                    Cl[o] = f2bf(v - bf2f(h));
                }
            }
        }
    }
}

// ============ 128x256 phase-split pipelined kernel (non-causal) ==============
// 8 waves (2M x 4N), wave tile 64x64. Per k-tile (BK=32): 2 phases x 24 MFMA.
// LDS: 3 buffers x {AsH 8K | AsL 8K | BsH 16K | BsL 16K} = 144 KiB.
// Stage depth 2; counted vmcnt(6) at iteration end (never 0 mid-loop).
// Chunk-XOR swizzle: LDS 16B-chunk cp of row holds logical chunk cp^((row>>1)&3)
// (involution; applied on gload SOURCE and ds_read ADDR; LDS dest stays linear).
template <int EPI, int OUT, int SWZ_HS>
__global__ __launch_bounds__(512, 2)
void mfma_gemm_ps(const u16* __restrict__ Ah, const u16* __restrict__ Al,
                  const u16* __restrict__ Bh, const u16* __restrict__ Bl,
                  float* __restrict__ Cf, u16* __restrict__ Ch, u16* __restrict__ Cl,
                  const float* __restrict__ bias, const float* __restrict__ resid,
                  int M, int N, int K, float alpha)
{
    int bx = blockIdx.x, by = blockIdx.y;
    if (SWZ_HS > 0) {
        const int GX = gridDim.x, GY = gridDim.y;
        const int g   = bx + GX * by;
        const int xcd = g & 7;
        const int li  = g >> 3;
        const int RB  = GY >> 3;
        const int rr_ = li % SWZ_HS;
        const int cc_ = (li / SWZ_HS) % GX;
        const int ss_ = li / (SWZ_HS * GX);
        by = xcd * RB + ss_ * SWZ_HS + rr_;
        bx = cc_;
    }
    const int rowStart = by * 128;
    const int colStart = bx * 256;

    __shared__ __align__(16) char lds[3 * 49152];  // 144 KiB

    const int tid = threadIdx.x;
    const int l  = tid & 63;
    const int w  = tid >> 6;      // 8 waves
    const int wr = w >> 2;        // 0..1  (M half)
    const int wc = w & 3;         // 0..3  (N quarter)
    const int fr = l & 15;
    const int ck = l >> 4;        // logical k-chunk 0..3

    const int T = K >> 5;         // k-tiles of 32

    const f32x4 fz = {0.f, 0.f, 0.f, 0.f};
    f32x4 acc[4][4];
#pragma unroll
    for (int m = 0; m < 4; ++m)
#pragma unroll
        for (int n = 0; n < 4; ++n) acc[m][n] = fz;

    // stage one 16B granule g of a tile region (A: 512 granules, B: 1024)
    auto stage_g = [&](const u16* __restrict__ src, int rowBase, int g,
                       char* region, int kb) {
        int row = g >> 2, cp = g & 3;
        int ko  = (cp ^ ((row >> 1) & 3)) << 3;  // logical source chunk, elems
        gld_lds16(src + (size_t)(rowBase + row) * K + kb + ko, region + g * 16);
    };
    // swizzled fragment read: logical chunk ck of row
    auto rd = [&](const char* region, int row) -> bf16x8 {
        return *(const bf16x8*)(region + row * 64 + ((ck ^ ((row >> 1) & 3)) << 4));
    };

    // -------- prologue: stage k-tiles 0 and 1 --------
    {
        char* b0 = lds;
        char* b1 = lds + 49152;
        stage_g(Ah, rowStart, tid,       b0 + 0,     0);
        stage_g(Al, rowStart, tid,       b0 + 8192,  0);
        stage_g(Bh, colStart, tid,       b0 + 16384, 0);
        stage_g(Bh, colStart, tid + 512, b0 + 16384, 0);
        stage_g(Bl, colStart, tid,       b0 + 32768, 0);
        stage_g(Bl, colStart, tid + 512, b0 + 32768, 0);
        stage_g(Ah, rowStart, tid,       b1 + 0,     32);
        stage_g(Al, rowStart, tid,       b1 + 8192,  32);
        stage_g(Bh, colStart, tid,       b1 + 16384, 32);
        stage_g(Bh, colStart, tid + 512, b1 + 16384, 32);
        stage_g(Bl, colStart, tid,       b1 + 32768, 32);
        stage_g(Bl, colStart, tid + 512, b1 + 32768, 32);
    }
    asm volatile("s_waitcnt vmcnt(6)" ::: "memory");  // tile 0 resident (own wave)
    __builtin_amdgcn_s_barrier();                     // -> all waves' tile 0 in

    for (int t = 0; t < T; ++t) {
        const char* cb = lds + (t % 3) * 49152;
        char*       sb = lds + ((t + 2) % 3) * 49152;
        const bool  doStage = (t + 2) < T;
        const int   kb2 = (t + 2) << 5;

        // ---------- phase 0: all A frags + B n=0,1 ----------
        bf16x8 aH[4], aL[4];
#pragma unroll
        for (int m = 0; m < 4; ++m) {
            aH[m] = rd(cb + 0,    wr * 64 + m * 16 + fr);
            aL[m] = rd(cb + 8192, wr * 64 + m * 16 + fr);
        }
        bf16x8 bH0 = rd(cb + 16384, wc * 64 + 0 * 16 + fr);
        bf16x8 bH1 = rd(cb + 16384, wc * 64 + 1 * 16 + fr);
        bf16x8 bL0 = rd(cb + 32768, wc * 64 + 0 * 16 + fr);
        bf16x8 bL1 = rd(cb + 32768, wc * 64 + 1 * 16 + fr);
        if (doStage) {
            stage_g(Ah, rowStart, tid, sb + 0,     kb2);
            stage_g(Al, rowStart, tid, sb + 8192,  kb2);
            stage_g(Bh, colStart, tid, sb + 16384, kb2);
        }
        __builtin_amdgcn_s_barrier();
        asm volatile("s_waitcnt lgkmcnt(0)" ::: "memory");
        __builtin_amdgcn_s_setprio(1);
#pragma unroll
        for (int m = 0; m < 4; ++m) {
            acc[m][0] = __builtin_amdgcn_mfma_f32_16x16x32_bf16(aH[m], bH0, acc[m][0], 0, 0, 0);
            acc[m][0] = __builtin_amdgcn_mfma_f32_16x16x32_bf16(aH[m], bL0, acc[m][0], 0, 0, 0);
            acc[m][0] = __builtin_amdgcn_mfma_f32_16x16x32_bf16(aL[m], bH0, acc[m][0], 0, 0, 0);
            acc[m][1] = __builtin_amdgcn_mfma_f32_16x16x32_bf16(aH[m], bH1, acc[m][1], 0, 0, 0);
            acc[m][1] = __builtin_amdgcn_mfma_f32_16x16x32_bf16(aH[m], bL1, acc[m][1], 0, 0, 0);
            acc[m][1] = __builtin_amdgcn_mfma_f32_16x16x32_bf16(aL[m], bH1, acc[m][1], 0, 0, 0);
        }
        __builtin_amdgcn_s_setprio(0);
        __builtin_amdgcn_s_barrier();

        // ---------- phase 1: B n=2,3 (A frags reused) ----------
        bf16x8 bH2 = rd(cb + 16384, wc * 64 + 2 * 16 + fr);
        bf16x8 bH3 = rd(cb + 16384, wc * 64 + 3 * 16 + fr);
        bf16x8 bL2 = rd(cb + 32768, wc * 64 + 2 * 16 + fr);
        bf16x8 bL3 = rd(cb + 32768, wc * 64 + 3 * 16 + fr);
        if (doStage) {
            stage_g(Bh, colStart, tid + 512, sb + 16384, kb2);
            stage_g(Bl, colStart, tid,       sb + 32768, kb2);
            stage_g(Bl, colStart, tid + 512, sb + 32768, kb2);
        }
        __builtin_amdgcn_s_barrier();
        asm volatile("s_waitcnt lgkmcnt(0)" ::: "memory");
        __builtin_amdgcn_s_setprio(1);
#pragma unroll
        for (int m = 0; m < 4; ++m) {
            acc[m][2] = __builtin_amdgcn_mfma_f32_16x16x32_bf16(aH[m], bH2, acc[m][2], 0, 0, 0);
            acc[m][2] = __builtin_amdgcn_mfma_f32_16x16x32_bf16(aH[m], bL2, acc[m][2], 0, 0, 0);
            acc[m][2] = __builtin_amdgcn_mfma_f32_16x16x32_bf16(aL[m], bH2, acc[m][2], 0, 0, 0);
            acc[m][3] = __builtin_amdgcn_mfma_f32_16x16x32_bf16(aH[m], bH3, acc[m][3], 0, 0, 0);
            acc[m][3] = __builtin_amdgcn_mfma_f32_16x16x32_bf16(aH[m], bL3, acc[m][3], 0, 0, 0);
            acc[m][3] = __builtin_amdgcn_mfma_f32_16x16x32_bf16(aL[m], bH3, acc[m][3], 0, 0, 0);
        }
        __builtin_amdgcn_s_setprio(0);
        // own wave: next tile resident; 6 newest (tile t+2) may stay in flight
        if (doStage) asm volatile("s_waitcnt vmcnt(6)" ::: "memory");
        else         asm volatile("s_waitcnt vmcnt(0)" ::: "memory");
        __builtin_amdgcn_s_barrier();   // -> all waves' next tile resident
    }

    // -------- epilogue --------
#pragma unroll
    for (int m = 0; m < 4; ++m) {
#pragma unroll
        for (int n = 0; n < 4; ++n) {
            const int col = colStart + wc * 64 + n * 16 + fr;
            float bv = 0.f;
            if (EPI >= 1) bv = bias[col];
#pragma unroll
            for (int rr = 0; rr < 4; ++rr) {
                const int row = rowStart + wr * 64 + m * 16 + (l >> 4) * 4 + rr;
                float v = acc[m][n][rr] * alpha;
                if (EPI >= 1) v += bv;
                if (EPI == 2) v = 0.5f * v * (1.0f + erff(v * 0.70710678118654752f));
                if (EPI == 3) v += resid[(size_t)row * N + col];
                if (OUT == 0) {
                    Cf[(size_t)row * N + col] = v;
                } else if (OUT == 1) {
                    size_t o = (size_t)row * N + col;
                    u16 h = f2bf(v);
                    Ch[o] = h;
                    Cl[o] = f2bf(v - bf2f(h));
                } else {
                    int b = row >> 11, tt = row & (SEQ_ - 1);
                    size_t o = ((size_t)b << 21) + ((size_t)col << 11) + tt;
                    u16 h = f2bf(v);
                    Ch[o] = h;
                    Cl[o] = f2bf(v - bf2f(h));
                }
            }
        }
    }
}

// ======================= prep: split / transpose-split =======================
__global__ __launch_bounds__(256)
void split_f32(const float* __restrict__ in, u16* __restrict__ oh, u16* __restrict__ ol, long n4)
{
    long i  = (long)blockIdx.x * 256 + threadIdx.x;
    long st = (long)gridDim.x * 256;
    for (; i < n4; i += st) {
        float4 v = ((const float4*)in)[i];
        ushort4 h, lo;
        h.x = f2bf(v.x); lo.x = f2bf(v.x - bf2f(h.x));
        h.y = f2bf(v.y); lo.y = f2bf(v.y - bf2f(h.y));
        h.z = f2bf(v.z); lo.z = f2bf(v.z - bf2f(h.z));
        h.w = f2bf(v.w); lo.w = f2bf(v.w - bf2f(h.w));
        ((ushort4*)oh)[i] = h;
        ((ushort4*)ol)[i] = lo;
    }
}

__global__ __launch_bounds__(256)
void transpose_split(const float* __restrict__ in, u16* __restrict__ oh, u16* __restrict__ ol,
                     int R, int C)
{
    __shared__ float t[32][33];
    const int c0 = blockIdx.x * 32, r0 = blockIdx.y * 32;
    const int tx = threadIdx.x, ty = threadIdx.y;
#pragma unroll
    for (int s = 0; s < 4; ++s)
        t[ty + s * 8][tx] = in[(size_t)(r0 + ty + s * 8) * C + c0 + tx];
    __syncthreads();
#pragma unroll
    for (int s = 0; s < 4; ++s) {
        int cl = ty + s * 8;
        float v = t[tx][cl];
        size_t o = (size_t)(c0 + cl) * R + r0 + tx;
        u16 h = f2bf(v);
        oh[o] = h;
        ol[o] = f2bf(v - bf2f(h));
    }
}

// ============== causal softmax, in place on split score arrays ===============
__global__ __launch_bounds__(256)
void softmax_split(u16* __restrict__ hi, u16* __restrict__ lo)
{
    const int row = blockIdx.x;
    const int b   = row >> 11;
    const int i   = row & (SEQ_ - 1);
    u16* ph = hi + ((size_t)b * SEQ_ + i) * SEQ_;
    u16* pl = lo + ((size_t)b * SEQ_ + i) * SEQ_;
    const int len = i + 1;
    const int lenPad = (len + 127) & ~127;
    const int tid = threadIdx.x;
    __shared__ float buf[SEQ_];
    __shared__ float red[256];

    float m = -INFINITY;
    for (int j = tid; j < len; j += 256) {
        float s = bf2f(ph[j]) + bf2f(pl[j]);
        buf[j] = s;
        m = fmaxf(m, s);
    }
    red[tid] = m; __syncthreads();
    for (int o = 128; o > 0; o >>= 1) { if (tid < o) red[tid] = fmaxf(red[tid], red[tid + o]); __syncthreads(); }
    m = red[0]; __syncthreads();

    float sum = 0.f;
    for (int j = tid; j < len; j += 256) { float e = expf(buf[j] - m); buf[j] = e; sum += e; }
    red[tid] = sum; __syncthreads();
    for (int o = 128; o > 0; o >>= 1) { if (tid < o) red[tid] += red[tid + o]; __syncthreads(); }
    const float inv = 1.0f / red[0];

    for (int j = tid; j < len; j += 256) {
        float p = buf[j] * inv;
        u16 h = f2bf(p);
        ph[j] = h;
        pl[j] = f2bf(p - bf2f(h));
    }
    for (int j = len + tid; j < lenPad; j += 256) { ph[j] = 0; pl[j] = 0; }
}

// ============ fused residual + LayerNorm (+ optional split output) ===========
__global__ __launch_bounds__(256)
void ln_kernel(const float* __restrict__ a, const float* __restrict__ r,
               const float* __restrict__ g, const float* __restrict__ beta,
               float* __restrict__ out, u16* __restrict__ oh, u16* __restrict__ ol)
{
    const int row = blockIdx.x, tid = threadIdx.x;
    float4 v = ((const float4*)(a + (size_t)row * D_MODEL))[tid];
    if (r) {
        float4 wv = ((const float4*)(r + (size_t)row * D_MODEL))[tid];
        v.x += wv.x; v.y += wv.y; v.z += wv.z; v.w += wv.w;
    }
    __shared__ float red[256];
    red[tid] = v.x + v.y + v.z + v.w; __syncthreads();
    for (int o = 128; o > 0; o >>= 1) { if (tid < o) red[tid] += red[tid + o]; __syncthreads(); }
    const float mu = red[0] * (1.0f / D_MODEL);
    __syncthreads();
    const float dx = v.x - mu, dy = v.y - mu, dz = v.z - mu, dw = v.w - mu;
    red[tid] = dx * dx + dy * dy + dz * dz + dw * dw; __syncthreads();
    for (int o = 128; o > 0; o >>= 1) { if (tid < o) red[tid] += red[tid + o]; __syncthreads(); }
    const float rs = rsqrtf(red[0] * (1.0f / D_MODEL) + 1e-5f);
    const float4 gv = ((const float4*)g)[tid];
    const float4 bv = ((const float4*)beta)[tid];
    float4 o4 = make_float4(dx * rs * gv.x + bv.x, dy * rs * gv.y + bv.y,
                            dz * rs * gv.z + bv.z, dw * rs * gv.w + bv.w);
    ((float4*)(out + (size_t)row * D_MODEL))[tid] = o4;
    if (oh) {
        ushort4 h, lo;
        h.x = f2bf(o4.x); lo.x = f2bf(o4.x - bf2f(h.x));
        h.y = f2bf(o4.y); lo.y = f2bf(o4.y - bf2f(h.y));
        h.z = f2bf(o4.z); lo.z = f2bf(o4.z - bf2f(h.z));
        h.w = f2bf(o4.w); lo.w = f2bf(o4.w - bf2f(h.w));
        ((ushort4*)(oh + (size_t)row * D_MODEL))[tid] = h;
        ((ushort4*)(ol + (size_t)row * D_MODEL))[tid] = lo;
    }
}

// ================================ launch =====================================
// Workspace arena (MB offsets), lifetime-overlapped; peak 204 MB.
extern "C" void kernel_launch(void* const* d_in, const int* in_sizes, int n_in,
                              void* d_out, int out_size, void* d_ws, size_t ws_size,
                              hipStream_t stream)
{
    const float* x    = (const float*)d_in[0];
    const float* Wq   = (const float*)d_in[1];
    const float* Wk   = (const float*)d_in[2];
    const float* Wv   = (const float*)d_in[3];
    const float* ln1g = (const float*)d_in[4];
    const float* ln1b = (const float*)d_in[5];
    const float* ln2g = (const float*)d_in[6];
    const float* ln2b = (const float*)d_in[7];
    const float* W1   = (const float*)d_in[8];
    const float* b1   = (const float*)d_in[9];
    const float* W2   = (const float*)d_in[10];
    const float* b2   = (const float*)d_in[11];

    const int Mrows = NBATCH * SEQ_; // 8192

    char* wsb = (char*)d_ws;
    auto U = [&](size_t mb) { return (u16*)(wsb + mb * (size_t)(1 << 20)); };
    u16 *WqTh = U(0),   *WqTl = U(2);
    u16 *WkTh = U(4),   *WkTl = U(6);
    u16 *WvTh = U(8),   *WvTl = U(10);
    u16 *xsh  = U(12),  *xsl  = U(28);
    float* attn = (float*)(wsb + 12 * (size_t)(1 << 20));
    u16 *W1Th = U(12),  *W1Tl = U(20);
    u16 *W2Th = U(28),  *W2Tl = U(36);
    u16 *Qsh  = U(44),  *Qsl  = U(60);
    u16 *hsh  = U(44),  *hsl  = U(60);
    u16 *Ksh  = U(76),  *Ksl  = U(92);
    u16 *Vth  = U(108), *Vtl  = U(124);
    u16 *Ssh  = U(140), *Ssl  = U(172);
    u16 *fh   = U(76),  *fl   = U(140);
    float* h  = (float*)d_out;

    dim3 b256(256), b512(512), tb(32, 8);

    transpose_split<<<dim3(32, 32), tb, 0, stream>>>(Wq, WqTh, WqTl, 1024, 1024);
    transpose_split<<<dim3(32, 32), tb, 0, stream>>>(Wk, WkTh, WkTl, 1024, 1024);
    transpose_split<<<dim3(32, 32), tb, 0, stream>>>(Wv, WvTh, WvTl, 1024, 1024);
    split_f32<<<dim3(2048), b256, 0, stream>>>(x, xsh, xsl, (long)Mrows * D_MODEL / 4);

    // Q/K/V projections on the pipelined kernel (grid 4x64 = 256 blocks)
    mfma_gemm_ps<0, 1, 4><<<dim3(4, 64), b512, 0, stream>>>(
        xsh, xsl, WqTh, WqTl, nullptr, Qsh, Qsl, nullptr, nullptr,
        Mrows, D_MODEL, D_MODEL, 1.f);
    mfma_gemm_ps<0, 1, 4><<<dim3(4, 64), b512, 0, stream>>>(
        xsh, xsl, WkTh, WkTl, nullptr, Ksh, Ksl, nullptr, nullptr,
        Mrows, D_MODEL, D_MODEL, 1.f);
    mfma_gemm_ps<0, 2, 4><<<dim3(4, 64), b512, 0, stream>>>(   // V -> Vt split (OUT=2)
        xsh, xsl, WvTh, WvTl, nullptr, Vth, Vtl, nullptr, nullptr,
        Mrows, D_MODEL, D_MODEL, 1.f);

    // scores = Q@K^T/32 (causal tiles) on proven 2-barrier kernel
    mfma_gemm<1, 0, 1, 0><<<dim3(16, 16, NBATCH), b256, 0, stream>>>(
        Qsh, Qsl, Ksh, Ksl, nullptr, Ssh, Ssl, nullptr, nullptr,
        SEQ_, SEQ_, D_MODEL, (long)SEQ_ * D_MODEL, (long)SEQ_ * D_MODEL,
        (long)SEQ_ * SEQ_, 0.03125f);
    softmax_split<<<dim3(Mrows), b256, 0, stream>>>(Ssh, Ssl);

    // attn = P@V (K causal-limited)
    mfma_gemm<2, 0, 0, 0><<<dim3(8, 16, NBATCH), b256, 0, stream>>>(
        Ssh, Ssl, Vth, Vtl, attn, nullptr, nullptr, nullptr, nullptr,
        SEQ_, D_MODEL, SEQ_, (long)SEQ_ * SEQ_, (long)D_MODEL * SEQ_,
        (long)SEQ_ * D_MODEL, 1.f);

    ln_kernel<<<dim3(Mrows), b256, 0, stream>>>(x, attn, ln1g, ln1b, h, hsh, hsl);

    transpose_split<<<dim3(128, 32), tb, 0, stream>>>(W1, W1Th, W1Tl, 1024, 4096);
    transpose_split<<<dim3(32, 128), tb, 0, stream>>>(W2, W2Th, W2Tl, 4096, 1024);

    // ffh = gelu(h@W1+b1), grid 16x64
    mfma_gemm_ps<2, 1, 4><<<dim3(16, 64), b512, 0, stream>>>(
        hsh, hsl, W1Th, W1Tl, nullptr, fh, fl, b1, nullptr,
        Mrows, DFF_, D_MODEL, 1.f);

    // out_pre = ffh@W2 + b2 + h, grid 4x64
    mfma_gemm_ps<3, 0, 1><<<dim3(4, 64), b512, 0, stream>>>(
        fh, fl, W2Th, W2Tl, (float*)d_out, nullptr, nullptr, b2, h,
        Mrows, D_MODEL, DFF_, 1.f);

    ln_kernel<<<dim3(Mrows), b256, 0, stream>>>(
        (const float*)d_out, nullptr, ln2g, ln2b, (float*)d_out, nullptr, nullptr);
}

// Round 8
// 919.798 us; speedup vs baseline: 1.1327x; 1.0327x over previous
//
#include <hip/hip_runtime.h>
#include <math.h>

// SimpleAttentionBlock fp32 -> bf16x3 split-GEMM on MFMA (gfx950).
// Round 8: single-barrier-per-k-tile pipeline (compiler-interleaved ds_read/MFMA,
// counted vmcnt(6), sched_barrier fence). All five GEMMs (QKV/scores/PV/FFN1/FFN2)
// now use the 128x256 8-wave ps kernel; causal handled by tile-skip (scores)
// and k-limit (PV).

#define D_MODEL 1024
#define DFF_    4096
#define SEQ_    2048
#define NBATCH  4

typedef unsigned short u16;
typedef __attribute__((ext_vector_type(8))) short bf16x8;
typedef __attribute__((ext_vector_type(4))) float f32x4;

__device__ __forceinline__ u16 f2bf(float f) {
    unsigned u = __float_as_uint(f);
    unsigned r = (u + 0x7fffu + ((u >> 16) & 1u)) >> 16;
    return (u16)r;
}
__device__ __forceinline__ float bf2f(u16 h) {
    return __uint_as_float(((unsigned)h) << 16);
}

// ---- async 16B global->LDS. LDS dest: wave-uniform base + lane*16.
__device__ __forceinline__ void gld_lds16(const void* g, void* l) {
#if __has_builtin(__builtin_amdgcn_global_load_lds)
    typedef __attribute__((address_space(1))) const unsigned int as1_u32;
    typedef __attribute__((address_space(3))) unsigned int as3_u32;
    __builtin_amdgcn_global_load_lds((as1_u32*)g, (as3_u32*)l, 16, 0, 0);
#else
    *(bf16x8*)l = *(const bf16x8*)g;
#endif
}

// ============ 128x256 pipelined bf16x3 GEMM (all GEMMs) ======================
// 8 waves (2M x 4N), wave tile 64x64. Per k-tile (BK=32): 48 MFMA, 16 ds_read,
// 6 global_load_lds (depth-2 prefetch). ONE barrier per k-tile:
//   { stage t+2 || frag reads(t) || 48 MFMA }  -> vmcnt(6) -> s_barrier -> SGB(0)
// Intra-tile ordering is left to the compiler (auto fine-grained lgkmcnt
// interleaves LDS reads with MFMA). Accumulation order per acc element is
// unchanged vs round 7 -> bitwise-identical results.
// LDS: 3 buffers x {AsH 8K | AsL 8K | BsH 16K | BsL 16K} = 144 KiB (1 block/CU).
// Chunk-XOR swizzle (involution, source+read side, linear LDS dest).
// CAUSAL: 0 none | 1 skip tiles colStart>=rowStart+128 | 2 K limited to rowStart+128
template <int CAUSAL, int EPI, int OUT, int SWZ_HS>
__global__ __launch_bounds__(512)
void mfma_gemm_ps(const u16* __restrict__ Ah, const u16* __restrict__ Al,
                  const u16* __restrict__ Bh, const u16* __restrict__ Bl,
                  float* __restrict__ Cf, u16* __restrict__ Ch, u16* __restrict__ Cl,
                  const float* __restrict__ bias, const float* __restrict__ resid,
                  int N, int K, long bA, long bB, long bC, float alpha)
{
    const int z = blockIdx.z;
    int bx = blockIdx.x, by = blockIdx.y;
    if (SWZ_HS > 0) {
        const int GX = gridDim.x, GY = gridDim.y;
        const int g   = bx + GX * by;
        const int xcd = g & 7;
        const int li  = g >> 3;
        const int RB  = GY >> 3;
        const int rr_ = li % SWZ_HS;
        const int cc_ = (li / SWZ_HS) % GX;
        const int ss_ = li / (SWZ_HS * GX);
        by = xcd * RB + ss_ * SWZ_HS + rr_;
        bx = cc_;
    }
    const int rowStart = by * 128;
    const int colStart = bx * 256;
    if (CAUSAL == 1 && colStart >= rowStart + 128) return;

    const u16* Ah_ = Ah + bA * z;
    const u16* Al_ = Al + bA * z;
    const u16* Bh_ = Bh + bB * z;
    const u16* Bl_ = Bl + bB * z;

    __shared__ __align__(16) char lds[3 * 49152];  // 144 KiB

    const int tid = threadIdx.x;
    const int l  = tid & 63;
    const int w  = tid >> 6;      // 8 waves
    const int wr = w >> 2;        // 0..1  (M half)
    const int wc = w & 3;         // 0..3  (N quarter)
    const int fr = l & 15;
    const int ck = l >> 4;        // logical k-chunk 0..3

    int T = K >> 5;               // k-tiles of 32
    if (CAUSAL == 2) {
        int kEnd = rowStart + 128;             // == lenPad for every row in block
        if (kEnd > K) kEnd = K;
        T = kEnd >> 5;
    }

    const f32x4 fz = {0.f, 0.f, 0.f, 0.f};
    f32x4 acc[4][4];
#pragma unroll
    for (int m = 0; m < 4; ++m)
#pragma unroll
        for (int n = 0; n < 4; ++n) acc[m][n] = fz;

    // stage one 16B granule g of a tile region (A: 512 granules, B: 1024)
    auto stage_g = [&](const u16* __restrict__ src, int rowBase, int g,
                       char* region, int kb) {
        int row = g >> 2, cp = g & 3;
        int ko  = (cp ^ ((row >> 1) & 3)) << 3;  // logical source chunk, elems
        gld_lds16(src + (size_t)(rowBase + row) * K + kb + ko, region + g * 16);
    };
    // swizzled fragment read: logical chunk ck of row
    auto rd = [&](const char* region, int row) -> bf16x8 {
        return *(const bf16x8*)(region + row * 64 + ((ck ^ ((row >> 1) & 3)) << 4));
    };

    // -------- prologue: stage k-tiles 0 and 1 --------
    {
        char* b0 = lds;
        char* b1 = lds + 49152;
        stage_g(Ah_, rowStart, tid,       b0 + 0,     0);
        stage_g(Al_, rowStart, tid,       b0 + 8192,  0);
        stage_g(Bh_, colStart, tid,       b0 + 16384, 0);
        stage_g(Bh_, colStart, tid + 512, b0 + 16384, 0);
        stage_g(Bl_, colStart, tid,       b0 + 32768, 0);
        stage_g(Bl_, colStart, tid + 512, b0 + 32768, 0);
        stage_g(Ah_, rowStart, tid,       b1 + 0,     32);
        stage_g(Al_, rowStart, tid,       b1 + 8192,  32);
        stage_g(Bh_, colStart, tid,       b1 + 16384, 32);
        stage_g(Bh_, colStart, tid + 512, b1 + 16384, 32);
        stage_g(Bl_, colStart, tid,       b1 + 32768, 32);
        stage_g(Bl_, colStart, tid + 512, b1 + 32768, 32);
    }
    asm volatile("s_waitcnt vmcnt(6)" ::: "memory");  // tile 0 resident (own wave)
    __builtin_amdgcn_s_barrier();                     // publish across waves
    __builtin_amdgcn_sched_barrier(0);

    for (int t = 0; t < T; ++t) {
        const char* cb = lds + (t % 3) * 49152;
        char*       sb = lds + ((t + 2) % 3) * 49152;
        const bool  doStage = (t + 2) < T;
        const int   kb2 = (t + 2) << 5;

        // issue depth-2 prefetch early (in flight during this tile's compute).
        // WAR-safe: all reads of buffer (t+2)%3 == (t-1)%3 completed before the
        // end-of-(t-1) barrier (each read feeds an MFMA preceding that barrier).
        if (doStage) {
            stage_g(Ah_, rowStart, tid,       sb + 0,     kb2);
            stage_g(Al_, rowStart, tid,       sb + 8192,  kb2);
            stage_g(Bh_, colStart, tid,       sb + 16384, kb2);
            stage_g(Bh_, colStart, tid + 512, sb + 16384, kb2);
            stage_g(Bl_, colStart, tid,       sb + 32768, kb2);
            stage_g(Bl_, colStart, tid + 512, sb + 32768, kb2);
        }

        // fragment reads + 48 MFMA: compiler interleaves with auto-lgkmcnt.
        bf16x8 aH[4], aL[4];
#pragma unroll
        for (int m = 0; m < 4; ++m) {
            aH[m] = rd(cb + 0,    wr * 64 + m * 16 + fr);
            aL[m] = rd(cb + 8192, wr * 64 + m * 16 + fr);
        }
        bf16x8 bH0 = rd(cb + 16384, wc * 64 + 0 * 16 + fr);
        bf16x8 bH1 = rd(cb + 16384, wc * 64 + 1 * 16 + fr);
        bf16x8 bL0 = rd(cb + 32768, wc * 64 + 0 * 16 + fr);
        bf16x8 bL1 = rd(cb + 32768, wc * 64 + 1 * 16 + fr);
#pragma unroll
        for (int m = 0; m < 4; ++m) {
            acc[m][0] = __builtin_amdgcn_mfma_f32_16x16x32_bf16(aH[m], bH0, acc[m][0], 0, 0, 0);
            acc[m][0] = __builtin_amdgcn_mfma_f32_16x16x32_bf16(aH[m], bL0, acc[m][0], 0, 0, 0);
            acc[m][0] = __builtin_amdgcn_mfma_f32_16x16x32_bf16(aL[m], bH0, acc[m][0], 0, 0, 0);
            acc[m][1] = __builtin_amdgcn_mfma_f32_16x16x32_bf16(aH[m], bH1, acc[m][1], 0, 0, 0);
            acc[m][1] = __builtin_amdgcn_mfma_f32_16x16x32_bf16(aH[m], bL1, acc[m][1], 0, 0, 0);
            acc[m][1] = __builtin_amdgcn_mfma_f32_16x16x32_bf16(aL[m], bH1, acc[m][1], 0, 0, 0);
        }
        bf16x8 bH2 = rd(cb + 16384, wc * 64 + 2 * 16 + fr);
        bf16x8 bH3 = rd(cb + 16384, wc * 64 + 3 * 16 + fr);
        bf16x8 bL2 = rd(cb + 32768, wc * 64 + 2 * 16 + fr);
        bf16x8 bL3 = rd(cb + 32768, wc * 64 + 3 * 16 + fr);
#pragma unroll
        for (int m = 0; m < 4; ++m) {
            acc[m][2] = __builtin_amdgcn_mfma_f32_16x16x32_bf16(aH[m], bH2, acc[m][2], 0, 0, 0);
            acc[m][2] = __builtin_amdgcn_mfma_f32_16x16x32_bf16(aH[m], bL2, acc[m][2], 0, 0, 0);
            acc[m][2] = __builtin_amdgcn_mfma_f32_16x16x32_bf16(aL[m], bH2, acc[m][2], 0, 0, 0);
            acc[m][3] = __builtin_amdgcn_mfma_f32_16x16x32_bf16(aH[m], bH3, acc[m][3], 0, 0, 0);
            acc[m][3] = __builtin_amdgcn_mfma_f32_16x16x32_bf16(aH[m], bL3, acc[m][3], 0, 0, 0);
            acc[m][3] = __builtin_amdgcn_mfma_f32_16x16x32_bf16(aL[m], bH3, acc[m][3], 0, 0, 0);
        }

        // end-of-iteration sync: own tile t+1 loads retired (counted, never 0
        // mid-loop), then block-wide publish; SGB(0) pins next-iter reads below.
        if (doStage) asm volatile("s_waitcnt vmcnt(6)" ::: "memory");
        else         asm volatile("s_waitcnt vmcnt(0)" ::: "memory");
        __builtin_amdgcn_s_barrier();
        __builtin_amdgcn_sched_barrier(0);
    }

    // -------- epilogue --------
#pragma unroll
    for (int m = 0; m < 4; ++m) {
#pragma unroll
        for (int n = 0; n < 4; ++n) {
            const int col = colStart + wc * 64 + n * 16 + fr;
            float bv = 0.f;
            if (EPI >= 1) bv = bias[col];
#pragma unroll
            for (int rr = 0; rr < 4; ++rr) {
                const int row = rowStart + wr * 64 + m * 16 + (l >> 4) * 4 + rr;
                float v = acc[m][n][rr] * alpha;
                if (EPI >= 1) v += bv;
                if (EPI == 2) v = 0.5f * v * (1.0f + erff(v * 0.70710678118654752f));
                if (EPI == 3) v += resid[(size_t)row * N + col];
                if (OUT == 0) {
                    Cf[bC * z + (size_t)row * N + col] = v;
                } else if (OUT == 1) {
                    size_t o = bC * z + (size_t)row * N + col;
                    u16 h = f2bf(v);
                    Ch[o] = h;
                    Cl[o] = f2bf(v - bf2f(h));
                } else { // OUT==2: V projection -> Vt [4][1024][2048]
                    int b = row >> 11, tt = row & (SEQ_ - 1);
                    size_t o = ((size_t)b << 21) + ((size_t)col << 11) + tt;
                    u16 h = f2bf(v);
                    Ch[o] = h;
                    Cl[o] = f2bf(v - bf2f(h));
                }
            }
        }
    }
}

// ======================= prep: split / transpose-split =======================
__global__ __launch_bounds__(256)
void split_f32(const float* __restrict__ in, u16* __restrict__ oh, u16* __restrict__ ol, long n4)
{
    long i  = (long)blockIdx.x * 256 + threadIdx.x;
    long st = (long)gridDim.x * 256;
    for (; i < n4; i += st) {
        float4 v = ((const float4*)in)[i];
        ushort4 h, lo;
        h.x = f2bf(v.x); lo.x = f2bf(v.x - bf2f(h.x));
        h.y = f2bf(v.y); lo.y = f2bf(v.y - bf2f(h.y));
        h.z = f2bf(v.z); lo.z = f2bf(v.z - bf2f(h.z));
        h.w = f2bf(v.w); lo.w = f2bf(v.w - bf2f(h.w));
        ((ushort4*)oh)[i] = h;
        ((ushort4*)ol)[i] = lo;
    }
}

__global__ __launch_bounds__(256)
void transpose_split(const float* __restrict__ in, u16* __restrict__ oh, u16* __restrict__ ol,
                     int R, int C)
{
    __shared__ float t[32][33];
    const int c0 = blockIdx.x * 32, r0 = blockIdx.y * 32;
    const int tx = threadIdx.x, ty = threadIdx.y;
#pragma unroll
    for (int s = 0; s < 4; ++s)
        t[ty + s * 8][tx] = in[(size_t)(r0 + ty + s * 8) * C + c0 + tx];
    __syncthreads();
#pragma unroll
    for (int s = 0; s < 4; ++s) {
        int cl = ty + s * 8;
        float v = t[tx][cl];
        size_t o = (size_t)(c0 + cl) * R + r0 + tx;
        u16 h = f2bf(v);
        oh[o] = h;
        ol[o] = f2bf(v - bf2f(h));
    }
}

// ============== causal softmax, in place on split score arrays ===============
__global__ __launch_bounds__(256)
void softmax_split(u16* __restrict__ hi, u16* __restrict__ lo)
{
    const int row = blockIdx.x;
    const int b   = row >> 11;
    const int i   = row & (SEQ_ - 1);
    u16* ph = hi + ((size_t)b * SEQ_ + i) * SEQ_;
    u16* pl = lo + ((size_t)b * SEQ_ + i) * SEQ_;
    const int len = i + 1;
    const int lenPad = (len + 127) & ~127;  // == PV's causal k-limit for this row
    const int tid = threadIdx.x;
    __shared__ float buf[SEQ_];
    __shared__ float red[256];

    float m = -INFINITY;
    for (int j = tid; j < len; j += 256) {
        float s = bf2f(ph[j]) + bf2f(pl[j]);
        buf[j] = s;
        m = fmaxf(m, s);
    }
    red[tid] = m; __syncthreads();
    for (int o = 128; o > 0; o >>= 1) { if (tid < o) red[tid] = fmaxf(red[tid], red[tid + o]); __syncthreads(); }
    m = red[0]; __syncthreads();

    float sum = 0.f;
    for (int j = tid; j < len; j += 256) { float e = expf(buf[j] - m); buf[j] = e; sum += e; }
    red[tid] = sum; __syncthreads();
    for (int o = 128; o > 0; o >>= 1) { if (tid < o) red[tid] += red[tid + o]; __syncthreads(); }
    const float inv = 1.0f / red[0];

    for (int j = tid; j < len; j += 256) {
        float p = buf[j] * inv;
        u16 h = f2bf(p);
        ph[j] = h;
        pl[j] = f2bf(p - bf2f(h));
    }
    for (int j = len + tid; j < lenPad; j += 256) { ph[j] = 0; pl[j] = 0; }
}

// ============ fused residual + LayerNorm (+ optional split output) ===========
__global__ __launch_bounds__(256)
void ln_kernel(const float* __restrict__ a, const float* __restrict__ r,
               const float* __restrict__ g, const float* __restrict__ beta,
               float* __restrict__ out, u16* __restrict__ oh, u16* __restrict__ ol)
{
    const int row = blockIdx.x, tid = threadIdx.x;
    float4 v = ((const float4*)(a + (size_t)row * D_MODEL))[tid];
    if (r) {
        float4 wv = ((const float4*)(r + (size_t)row * D_MODEL))[tid];
        v.x += wv.x; v.y += wv.y; v.z += wv.z; v.w += wv.w;
    }
    __shared__ float red[256];
    red[tid] = v.x + v.y + v.z + v.w; __syncthreads();
    for (int o = 128; o > 0; o >>= 1) { if (tid < o) red[tid] += red[tid + o]; __syncthreads(); }
    const float mu = red[0] * (1.0f / D_MODEL);
    __syncthreads();
    const float dx = v.x - mu, dy = v.y - mu, dz = v.z - mu, dw = v.w - mu;
    red[tid] = dx * dx + dy * dy + dz * dz + dw * dw; __syncthreads();
    for (int o = 128; o > 0; o >>= 1) { if (tid < o) red[tid] += red[tid + o]; __syncthreads(); }
    const float rs = rsqrtf(red[0] * (1.0f / D_MODEL) + 1e-5f);
    const float4 gv = ((const float4*)g)[tid];
    const float4 bv = ((const float4*)beta)[tid];
    float4 o4 = make_float4(dx * rs * gv.x + bv.x, dy * rs * gv.y + bv.y,
                            dz * rs * gv.z + bv.z, dw * rs * gv.w + bv.w);
    ((float4*)(out + (size_t)row * D_MODEL))[tid] = o4;
    if (oh) {
        ushort4 h, lo;
        h.x = f2bf(o4.x); lo.x = f2bf(o4.x - bf2f(h.x));
        h.y = f2bf(o4.y); lo.y = f2bf(o4.y - bf2f(h.y));
        h.z = f2bf(o4.z); lo.z = f2bf(o4.z - bf2f(h.z));
        h.w = f2bf(o4.w); lo.w = f2bf(o4.w - bf2f(h.w));
        ((ushort4*)(oh + (size_t)row * D_MODEL))[tid] = h;
        ((ushort4*)(ol + (size_t)row * D_MODEL))[tid] = lo;
    }
}

// ================================ launch =====================================
// Workspace arena (MB offsets), lifetime-overlapped; peak 204 MB.
extern "C" void kernel_launch(void* const* d_in, const int* in_sizes, int n_in,
                              void* d_out, int out_size, void* d_ws, size_t ws_size,
                              hipStream_t stream)
{
    const float* x    = (const float*)d_in[0];
    const float* Wq   = (const float*)d_in[1];
    const float* Wk   = (const float*)d_in[2];
    const float* Wv   = (const float*)d_in[3];
    const float* ln1g = (const float*)d_in[4];
    const float* ln1b = (const float*)d_in[5];
    const float* ln2g = (const float*)d_in[6];
    const float* ln2b = (const float*)d_in[7];
    const float* W1   = (const float*)d_in[8];
    const float* b1   = (const float*)d_in[9];
    const float* W2   = (const float*)d_in[10];
    const float* b2   = (const float*)d_in[11];

    const int Mrows = NBATCH * SEQ_; // 8192

    char* wsb = (char*)d_ws;
    auto U = [&](size_t mb) { return (u16*)(wsb + mb * (size_t)(1 << 20)); };
    u16 *WqTh = U(0),   *WqTl = U(2);
    u16 *WkTh = U(4),   *WkTl = U(6);
    u16 *WvTh = U(8),   *WvTl = U(10);
    u16 *xsh  = U(12),  *xsl  = U(28);
    float* attn = (float*)(wsb + 12 * (size_t)(1 << 20));
    u16 *W1Th = U(12),  *W1Tl = U(20);
    u16 *W2Th = U(28),  *W2Tl = U(36);
    u16 *Qsh  = U(44),  *Qsl  = U(60);
    u16 *hsh  = U(44),  *hsl  = U(60);
    u16 *Ksh  = U(76),  *Ksl  = U(92);
    u16 *Vth  = U(108), *Vtl  = U(124);
    u16 *Ssh  = U(140), *Ssl  = U(172);
    u16 *fh   = U(76),  *fl   = U(140);
    float* h  = (float*)d_out;

    dim3 b256(256), b512(512), tb(32, 8);

    transpose_split<<<dim3(32, 32), tb, 0, stream>>>(Wq, WqTh, WqTl, 1024, 1024);
    transpose_split<<<dim3(32, 32), tb, 0, stream>>>(Wk, WkTh, WkTl, 1024, 1024);
    transpose_split<<<dim3(32, 32), tb, 0, stream>>>(Wv, WvTh, WvTl, 1024, 1024);
    split_f32<<<dim3(2048), b256, 0, stream>>>(x, xsh, xsl, (long)Mrows * D_MODEL / 4);

    // Q/K/V projections (grid 4x64; V transposed via OUT=2)
    mfma_gemm_ps<0, 0, 1, 4><<<dim3(4, 64), b512, 0, stream>>>(
        xsh, xsl, WqTh, WqTl, nullptr, Qsh, Qsl, nullptr, nullptr,
        D_MODEL, D_MODEL, 0, 0, 0, 1.f);
    mfma_gemm_ps<0, 0, 1, 4><<<dim3(4, 64), b512, 0, stream>>>(
        xsh, xsl, WkTh, WkTl, nullptr, Ksh, Ksl, nullptr, nullptr,
        D_MODEL, D_MODEL, 0, 0, 0, 1.f);
    mfma_gemm_ps<0, 0, 2, 4><<<dim3(4, 64), b512, 0, stream>>>(
        xsh, xsl, WvTh, WvTl, nullptr, Vth, Vtl, nullptr, nullptr,
        D_MODEL, D_MODEL, 0, 0, 0, 1.f);

    // scores = Q@K^T/32 (causal tile-skip), grid 8x16x4
    mfma_gemm_ps<1, 0, 1, 0><<<dim3(8, 16, NBATCH), b512, 0, stream>>>(
        Qsh, Qsl, Ksh, Ksl, nullptr, Ssh, Ssl, nullptr, nullptr,
        SEQ_, D_MODEL, (long)SEQ_ * D_MODEL, (long)SEQ_ * D_MODEL,
        (long)SEQ_ * SEQ_, 0.03125f);
    softmax_split<<<dim3(Mrows), b256, 0, stream>>>(Ssh, Ssl);

    // attn = P@V (k-limit), grid 4x16x4
    mfma_gemm_ps<2, 0, 0, 0><<<dim3(4, 16, NBATCH), b512, 0, stream>>>(
        Ssh, Ssl, Vth, Vtl, attn, nullptr, nullptr, nullptr, nullptr,
        D_MODEL, SEQ_, (long)SEQ_ * SEQ_, (long)D_MODEL * SEQ_,
        (long)SEQ_ * D_MODEL, 1.f);

    ln_kernel<<<dim3(Mrows), b256, 0, stream>>>(x, attn, ln1g, ln1b, h, hsh, hsl);

    transpose_split<<<dim3(128, 32), tb, 0, stream>>>(W1, W1Th, W1Tl, 1024, 4096);
    transpose_split<<<dim3(32, 128), tb, 0, stream>>>(W2, W2Th, W2Tl, 4096, 1024);

    // ffh = gelu(h@W1+b1), grid 16x64
    mfma_gemm_ps<0, 2, 1, 4><<<dim3(16, 64), b512, 0, stream>>>(
        hsh, hsl, W1Th, W1Tl, nullptr, fh, fl, b1, nullptr,
        DFF_, D_MODEL, 0, 0, 0, 1.f);

    // out_pre = ffh@W2 + b2 + h, grid 4x64
    mfma_gemm_ps<0, 3, 0, 1><<<dim3(4, 64), b512, 0, stream>>>(
        fh, fl, W2Th, W2Tl, (float*)d_out, nullptr, nullptr, b2, h,
        D_MODEL, DFF_, 0, 0, 0, 1.f);

    ln_kernel<<<dim3(Mrows), b256, 0, stream>>>(
        (const float*)d_out, nullptr, ln2g, ln2b, (float*)d_out, nullptr, nullptr);
}